// Round 5
// baseline (638.411 us; speedup 1.0000x reference)
//
#include <hip/hip_runtime.h>
#include <hip/hip_fp16.h>
#include <math.h>

#define NN 100000
#define NE 1200000
#define FIN 256
#define NBLK 391        // (NN + 255) / 256
#define HB 4688         // (NE + 255) / 256  -- histogram blocks
#define WB2 170         // (59904 - 16384) / 256 -- W-swizzle blocks (skip pre0)
#define GB64 1563       // (NN + 63) / 64  -- 64-row GEMM / layer blocks

using half8   = __attribute__((ext_vector_type(8))) _Float16;
using floatx4 = __attribute__((ext_vector_type(4))) float;

__device__ __forceinline__ floatx4 mfma16(half8 a, half8 b, floatx4 c) {
    return __builtin_amdgcn_mfma_f32_16x16x32_f16(a, b, c, 0, 0, 0);
}

// ---------------- W0 pre-swizzle (runs before k_prep so pre32 can read it) ----
__global__ __launch_bounds__(256) void k_wpre0(const float* __restrict__ W0,
                                               __half* __restrict__ Wf) {
    int o = blockIdx.x * 256 + threadIdx.x;   // 0..16383 exactly
    int j = o & 7, n = (o >> 3) & 15, q = (o >> 7) & 3, rest = o >> 9;
    int t = rest & 3, kc = rest >> 2;
    int k = kc * 32 + q * 8 + j, col = t * 16 + n;
    Wf[o] = __float2half(W0[(size_t)k * 64 + col]);
}

// ---------------- shared epilogue for pre-linear: store xh + att dots ---------
// asd row = {a_src0, a_src1, dinv, pad}; dinv slot untouched here.
__device__ __forceinline__ void pre_epi(floatx4* acc, const float* b, const float* attf,
                                        float* asd, float* a_dst, __half* out,
                                        int rowb, int q, int n) {
    float vs0[4] = {0,0,0,0}, vs1[4] = {0,0,0,0};
    float vd0[4] = {0,0,0,0}, vd1[4] = {0,0,0,0};
    #pragma unroll
    for (int t = 0; t < 4; ++t) {
        float bb  = b[t * 16 + n];
        float ws0 = attf[t * 16 + n],       ws1 = attf[64 + t * 16 + n];
        float wd0 = attf[128 + t * 16 + n], wd1 = attf[192 + t * 16 + n];
        #pragma unroll
        for (int r = 0; r < 4; ++r) {
            float xv = acc[t][r] + bb;
            int row = rowb + q * 4 + r;
            if (row < NN) out[(size_t)row * 64 + t * 16 + n] = __float2half(xv);
            vs0[r] = fmaf(xv, ws0, vs0[r]);
            vs1[r] = fmaf(xv, ws1, vs1[r]);
            vd0[r] = fmaf(xv, wd0, vd0[r]);
            vd1[r] = fmaf(xv, wd1, vd1[r]);
        }
    }
    #pragma unroll
    for (int off = 1; off < 16; off <<= 1) {
        #pragma unroll
        for (int r = 0; r < 4; ++r) {
            vs0[r] += __shfl_xor(vs0[r], off);
            vs1[r] += __shfl_xor(vs1[r], off);
            vd0[r] += __shfl_xor(vd0[r], off);
            vd1[r] += __shfl_xor(vd1[r], off);
        }
    }
    if (n == 0) {
        #pragma unroll
        for (int r = 0; r < 4; ++r) {
            int row = rowb + q * 4 + r;
            if (row < NN) {
                *(float2*)&asd[row * 4] = make_float2(vs0[r], vs1[r]);
                *(float2*)&a_dst[row * 2] = make_float2(vd0[r], vd1[r]);
            }
        }
    }
}

// ---------------- mega-prep: pre32 GEMM | histogram/ordinal | W swizzle -------
// pre32 blocks (MFMA-bound) co-scheduled with hist blocks (atomic-latency-bound)
// -> GEMM hides under atomics. Only 1KB static LDS: occupancy stays launch-bound.
// packed[d]: bits[48:63] = count, bits[0:47] = sum(w) in 2^-32 fixed point.
__global__ __launch_bounds__(256) void k_prep(const int* __restrict__ dst,
                                              const float* __restrict__ ew,
                                              unsigned long long* __restrict__ packed,
                                              int* __restrict__ ord,
                                              const float* __restrict__ x,
                                              const float* __restrict__ pre_b0,
                                              const float* __restrict__ W1,
                                              const float* __restrict__ Wg0,
                                              const float* __restrict__ Ws0,
                                              const float* __restrict__ Wg1,
                                              const float* __restrict__ Ws1,
                                              const float* __restrict__ Wc,
                                              const float* __restrict__ As0,
                                              const float* __restrict__ Ad0,
                                              const float* __restrict__ As1,
                                              const float* __restrict__ Ad1,
                                              __half* __restrict__ Wf,
                                              float* __restrict__ attf,
                                              float* __restrict__ asd0,
                                              float* __restrict__ adst0,
                                              __half* __restrict__ xh0) {
    __shared__ float attL[256];
    int bid = blockIdx.x;
    int tid = threadIdx.x;
    if (bid >= GB64) {
        int b2 = bid - GB64;
        if (b2 < HB) {
            // ---- edge histogram + ordinal capture ----
            int e = b2 * 256 + tid;
            if (e >= NE) return;
            int d = dst[e]; float w = ew[e];
            unsigned long long add = (1ULL << 48)
                + (unsigned long long)((double)w * 4294967296.0);
            unsigned long long old = atomicAdd(&packed[d], add);
            ord[e] = (int)(old >> 48);
            return;
        }
        // ---- W swizzle (pre1, pq0, pq1, cls) + folded att vectors ----
        int o = (b2 - HB) * 256 + tid + 16384;
        if (o >= 59904) return;
        if (o >= 59392) {
            int idx = o - 59392;          // 0..511
            int layer = idx >> 8, rem = idx & 255;
            int v = rem >> 6, c = rem & 63, h = v & 1;
            const float* Wg = layer ? Wg1 : Wg0;
            const float* av = (v < 2) ? (layer ? As1 : As0) : (layer ? Ad1 : Ad0);
            float s = 0.f;
            for (int jj = 0; jj < 64; ++jj)
                s = fmaf(Wg[c * 128 + h * 64 + jj], av[h * 64 + jj], s);
            attf[idx] = s;
            return;
        }
        int lo, NT, N; const float* Wg; const float* Wsg = nullptr;
        if (o < 28672)      { lo = o - 16384; NT = 4;  N = 64; Wg = W1; }
        else if (o < 40960) { lo = o - 28672; NT = 12; N = 0;  Wg = Wg0; Wsg = Ws0; }
        else if (o < 53248) { lo = o - 40960; NT = 12; N = 0;  Wg = Wg1; Wsg = Ws1; }
        else                { lo = o - 53248; NT = 2;  N = 32; Wg = Wc; }
        int j = lo & 7, n = (lo >> 3) & 15, q = (lo >> 7) & 3, rest = lo >> 9;
        int t = rest % NT, kc = rest / NT;
        int k = kc * 32 + q * 8 + j, col = t * 16 + n;
        float v;
        if (Wsg) v = (col < 128) ? Wg[(size_t)k * 128 + col] : Wsg[(size_t)k * 64 + (col - 128)];
        else     v = Wg[(size_t)k * N + col];
        Wf[o] = __float2half(v);
        return;
    }
    // ---- pre32: xh0 = x @ W0 + b -> fp16, + layer-0 att dots (attL in-block) --
    {
        int v = tid >> 6, c = tid & 63, h = v & 1;
        const float* av = (v < 2) ? As0 : Ad0;
        float s = 0.f;
        for (int jj = 0; jj < 64; ++jj)
            s = fmaf(Wg0[c * 128 + h * 64 + jj], av[h * 64 + jj], s);
        attL[tid] = s;
    }
    __syncthreads();
    int lane = tid & 63, wv = tid >> 6;
    int q = lane >> 4, n = lane & 15;
    int rowb = bid * 64 + wv * 16;
    int rowA = rowb + n; if (rowA > NN - 1) rowA = NN - 1;
    floatx4 acc[4] = {};
    const float* ap = x + (size_t)rowA * FIN + q * 8;
    const __half* wp = Wf + q * 128 + n * 8;
    #pragma unroll
    for (int kc = 0; kc < FIN / 32; ++kc) {
        float4 f0 = *(const float4*)(ap + kc * 32);
        float4 f1 = *(const float4*)(ap + kc * 32 + 4);
        half8 a;
        a[0] = (_Float16)f0.x; a[1] = (_Float16)f0.y;
        a[2] = (_Float16)f0.z; a[3] = (_Float16)f0.w;
        a[4] = (_Float16)f1.x; a[5] = (_Float16)f1.y;
        a[6] = (_Float16)f1.z; a[7] = (_Float16)f1.w;
        #pragma unroll
        for (int t = 0; t < 4; ++t) {
            half8 bf = *(const half8*)(wp + (size_t)(kc * 4 + t) * 512);
            acc[t] = mfma16(a, bf, acc[t]);
        }
    }
    pre_epi(acc, pre_b0, attL, asd0, adst0, xh0, rowb, q, n);
}

// ---------------- single-launch CSR scan: decoupled lookback ------------------
// Writes dinv into BOTH asd buffers (layer0 + layer1 views).
__global__ __launch_bounds__(256) void k_scan(const unsigned long long* __restrict__ packed,
                                              int* __restrict__ row_ptr,
                                              float* __restrict__ asd0,
                                              float* __restrict__ asd1,
                                              unsigned long long* __restrict__ desc) {
    __shared__ int tmp[256];
    __shared__ int exoff_sh;
    int tid = threadIdx.x, bid = blockIdx.x;
    int i = bid * 256 + tid;
    int v = 0;
    if (i < NN) {
        unsigned long long p = packed[i];
        v = (int)(p >> 48);
        // +1.0 = virtual self-loop weight; deg >= 1 always
        double deg = (double)(p & 0xFFFFFFFFFFFFULL) * (1.0 / 4294967296.0) + 1.0;
        float r = rsqrtf((float)deg);
        asd0[i * 4 + 2] = r;
        asd1[i * 4 + 2] = r;
    }
    tmp[tid] = v;
    __syncthreads();
    for (int off = 1; off < 256; off <<= 1) {
        int t = (tid >= off) ? tmp[tid - off] : 0;
        __syncthreads();
        tmp[tid] += t;
        __syncthreads();
    }
    int bsum = tmp[255];
    if (bid == 0) {
        if (tid == 0) {
            exoff_sh = 0;
            atomicExch(&desc[0], (2ULL << 32) | (unsigned long long)(unsigned)bsum);
            row_ptr[NN] = NE;
        }
    } else if (tid < 64) {
        if (tid == 0)
            atomicExch(&desc[bid], (1ULL << 32) | (unsigned long long)(unsigned)bsum);
        int sum = 0;
        int base = bid - 1;
        for (;;) {
            int j = base - tid;
            unsigned long long d = 0;
            bool have = (j >= 0);
            if (have) {
                do { d = atomicAdd((unsigned long long*)&desc[j], 0ULL); }
                while ((d >> 32) == 0ULL);
            }
            unsigned long long m2 = __ballot(have && ((d >> 32) == 2ULL));
            if (m2) {
                int stop = __ffsll((long long)m2) - 1;   // nearest inclusive entry
                if (tid <= stop) sum += (int)(d & 0xFFFFFFFFULL);
                break;
            }
            if (have) sum += (int)(d & 0xFFFFFFFFULL);
            base -= 64;
        }
        #pragma unroll
        for (int off = 32; off; off >>= 1) sum += __shfl_xor(sum, off);
        if (tid == 0) {
            exoff_sh = sum;
            atomicExch(&desc[bid],
                       (2ULL << 32) | (unsigned long long)(unsigned)(sum + bsum));
        }
    }
    __syncthreads();
    if (i < NN) row_ptr[i] = exoff_sh + tmp[tid] - v;
}

// ---------------- CSR fill: NO atomic, NO dinv gather -------------------------
__global__ __launch_bounds__(256) void k_fill(const int* __restrict__ src,
                                              const int* __restrict__ dst,
                                              const float* __restrict__ ew,
                                              const int* __restrict__ row_ptr,
                                              const int* __restrict__ ord,
                                              int2* __restrict__ recs) {
    int e = blockIdx.x * 256 + threadIdx.x;
    if (e >= NE) return;
    int d = dst[e];
    int pos = row_ptr[d] + ord[e];
    int2 r; r.x = src[e]; r.y = __float_as_int(ew[e]);
    recs[pos] = r;
}

// ---------------- per-node fused GAT+SG aggregation -> LDS tile row -----------
// one wave, one dst node. Result row = {g0(64)|g1(64)|sg(64)} fp16 in trow.
__device__ __forceinline__ void agg_node(int d, int lane, int sub, unsigned flb,
                                         const int* __restrict__ row_ptr,
                                         const int2* __restrict__ recs,
                                         const float4* __restrict__ asd4,
                                         const float* __restrict__ a_dst,
                                         const __half* __restrict__ xh,
                                         float4* __restrict__ einfoW,
                                         __half* __restrict__ trow) {
    int p0 = row_ptr[d], p1 = row_ptr[d + 1];
    int nn = p1 - p0;                 // real edges; +1 virtual self-loop
    float2 ad2 = ((const float2*)a_dst)[d];

    float g00 = 0.f, g01 = 0.f;   // head0 agg
    float g10 = 0.f, g11 = 0.f;   // head1 agg
    float s0a = 0.f, s1a = 0.f;   // sg agg

#define EDGE_ACC(E) do {                                                        \
        unsigned off_ = (unsigned)__float_as_int((E).w) + flb;                  \
        float2 v_ = __half22float2(*(const __half2*)((const char*)xh + off_));  \
        g00 = fmaf((E).x, v_.x, g00); g01 = fmaf((E).x, v_.y, g01);             \
        g10 = fmaf((E).y, v_.x, g10); g11 = fmaf((E).y, v_.y, g11);             \
        s0a = fmaf((E).z, v_.x, s0a); s1a = fmaf((E).z, v_.y, s1a);             \
    } while (0)

    if (nn <= 63) {
        // ---- fast path (max degree ~40 for this graph) ----
        int tot = nn + 1;
        float v0 = -INFINITY, v1 = -INFINITY, ewq = 0.f; int es = 0;
        if (lane < tot) {
            float wraw;
            if (lane < nn) {
                int2 rec = recs[p0 + lane];
                es = rec.x;
                wraw = __int_as_float(rec.y);
            } else { es = d; wraw = 1.f; }       // virtual self-loop
            float4 a4 = asd4[es];
            v0 = a4.x + ad2.x; v0 = (v0 > 0.f) ? v0 : 0.2f * v0;
            v1 = a4.y + ad2.y; v1 = (v1 > 0.f) ? v1 : 0.2f * v1;
            ewq = wraw * a4.z;                   // w * dinv[src]
        }
        float m0 = v0, m1 = v1;
        #pragma unroll
        for (int off = 32; off; off >>= 1) {
            m0 = fmaxf(m0, __shfl_xor(m0, off));
            m1 = fmaxf(m1, __shfl_xor(m1, off));
        }
        float e0 = (lane < tot) ? __expf(v0 - m0) : 0.f;
        float e1 = (lane < tot) ? __expf(v1 - m1) : 0.f;
        float s0 = e0, s1 = e1;
        #pragma unroll
        for (int off = 32; off; off >>= 1) {
            s0 += __shfl_xor(s0, off);
            s1 += __shfl_xor(s1, off);
        }
        if (lane < tot)
            einfoW[lane] = make_float4(e0 / (s0 + 1e-16f), e1 / (s1 + 1e-16f),
                                       ewq, __int_as_float(es << 7));
        // intra-wave LDS: DS pipe is in-order per wave, no barrier needed
        const float4* ep = einfoW + sub;
        int j = 0;
        for (; j + 4 <= tot; j += 4) {
            float4 eA = ep[j];
            float4 eB = ep[j + 2];
            EDGE_ACC(eA);
            EDGE_ACC(eB);
        }
        for (; j + 2 <= tot; j += 2) {
            float4 eA = ep[j];
            EDGE_ACC(eA);
        }
        if (tot & 1) {
            if (sub == 0) {
                float4 eT = einfoW[tot - 1];
                EDGE_ACC(eT);
            }
        }
    } else {
        // ---- generic 3-pass path (degree > 63; dead for this graph) ----
        float4 aself = asd4[d];
        float sv0 = aself.x + ad2.x; sv0 = (sv0 > 0.f) ? sv0 : 0.2f * sv0;
        float sv1 = aself.y + ad2.y; sv1 = (sv1 > 0.f) ? sv1 : 0.2f * sv1;
        float m0 = sv0, m1 = sv1;
        for (int e = p0 + lane; e < p1; e += 64) {
            int s = recs[e].x;
            float4 a4 = asd4[s];
            float v0 = a4.x + ad2.x; v0 = (v0 > 0.f) ? v0 : 0.2f * v0;
            float v1 = a4.y + ad2.y; v1 = (v1 > 0.f) ? v1 : 0.2f * v1;
            m0 = fmaxf(m0, v0); m1 = fmaxf(m1, v1);
        }
        #pragma unroll
        for (int off = 32; off; off >>= 1) {
            m0 = fmaxf(m0, __shfl_xor(m0, off));
            m1 = fmaxf(m1, __shfl_xor(m1, off));
        }
        float s0 = 0.f, s1 = 0.f;
        for (int e = p0 + lane; e < p1; e += 64) {
            int s = recs[e].x;
            float4 a4 = asd4[s];
            float v0 = a4.x + ad2.x; v0 = (v0 > 0.f) ? v0 : 0.2f * v0;
            float v1 = a4.y + ad2.y; v1 = (v1 > 0.f) ? v1 : 0.2f * v1;
            s0 += __expf(v0 - m0); s1 += __expf(v1 - m1);
        }
        #pragma unroll
        for (int off = 32; off; off >>= 1) {
            s0 += __shfl_xor(s0, off);
            s1 += __shfl_xor(s1, off);
        }
        s0 += __expf(sv0 - m0); s1 += __expf(sv1 - m1);   // self contribution
        float inv0 = 1.f / (s0 + 1e-16f), inv1 = 1.f / (s1 + 1e-16f);
        for (int base = p0; base < p1; base += 64) {
            int e = base + lane;
            int nc = min(64, p1 - base);
            if (e < p1) {
                int2 rec = recs[e];
                int es = rec.x;
                float4 a4 = asd4[es];
                float v0 = a4.x + ad2.x; v0 = (v0 > 0.f) ? v0 : 0.2f * v0;
                float v1 = a4.y + ad2.y; v1 = (v1 > 0.f) ? v1 : 0.2f * v1;
                einfoW[lane] = make_float4(__expf(v0 - m0) * inv0,
                                           __expf(v1 - m1) * inv1,
                                           __int_as_float(rec.y) * a4.z,
                                           __int_as_float(es << 7));
            }
            const float4* ep = einfoW + sub;
            int j = 0;
            for (; j + 2 <= nc; j += 2) {
                float4 eA = ep[j];
                EDGE_ACC(eA);
            }
            if (nc & 1) {
                if (sub == 0) {
                    float4 eT = einfoW[nc - 1];
                    EDGE_ACC(eT);
                }
            }
        }
        if (sub == 0) {   // virtual self-loop
            float4 eS = make_float4(__expf(sv0 - m0) * inv0,
                                    __expf(sv1 - m1) * inv1,
                                    aself.z, __int_as_float(d << 7));
            EDGE_ACC(eS);
        }
    }
#undef EDGE_ACC

    // combine the two half-wave partial sums
    g00 += __shfl_xor(g00, 32); g01 += __shfl_xor(g01, 32);
    g10 += __shfl_xor(g10, 32); g11 += __shfl_xor(g11, 32);
    s0a += __shfl_xor(s0a, 32); s1a += __shfl_xor(s1a, 32);

    float did = asd4[d].z;
    int fp = (lane & 31) * 2;
    if (lane < 32) {
        *(__half2*)(trow + fp)       = __floats2half2_rn(g00, g01);
        *(__half2*)(trow + 128 + fp) = __floats2half2_rn(s0a * did, s1a * did);
    } else {
        *(__half2*)(trow + 64 + fp)  = __floats2half2_rn(g10, g11);
    }
}

// ---------------- layer 0: agg(64 nodes) -> LDS -> post GEMM -> pre GEMM ------
// agg[NN][192] intermediate never touches HBM. All GEMM work is wave-local
// (wave wv owns tile rows wv*16..wv*16+15): NO barriers.
__global__ __launch_bounds__(256) void k_lay0(const int* __restrict__ row_ptr,
                                              const int2* __restrict__ recs,
                                              const float* __restrict__ asd_in,
                                              const float* __restrict__ adst_in,
                                              const __half* __restrict__ xh_in,
                                              const __half* __restrict__ Wfpq,
                                              const float* __restrict__ gat_b,
                                              const float* __restrict__ sg_b,
                                              const __half* __restrict__ Wfpre,
                                              const float* __restrict__ pre_b,
                                              const float* __restrict__ attf,
                                              float* __restrict__ asd_out,
                                              float* __restrict__ adst_out,
                                              __half* __restrict__ xh_out) {
    __shared__ __half tile[64][200];   // 192->200 stride: rows land on even banks
    __shared__ float4 einfo[4][64];
    int lane = threadIdx.x & 63, wv = threadIdx.x >> 6;
    int sub = lane >> 5;
    unsigned flb = (unsigned)(lane & 31) * 4u;
    const float4* asd4 = (const float4*)asd_in;
    int base = blockIdx.x * 64 + wv * 16;
    for (int i = 0; i < 16; ++i) {
        int d = base + i;
        __half* trow = &tile[wv * 16 + i][0];
        if (d < NN) {
            agg_node(d, lane, sub, flb, row_ptr, recs, asd4, adst_in, xh_in,
                     einfo[wv], trow);
        } else {
            for (int c = lane; c < 192; c += 64) trow[c] = __float2half(0.f);
        }
    }
    int q = lane >> 4, n = lane & 15;
    int rowb = base;
    {   // post GEMM: block-diag {g0@Wg[:,0:64] | g1@Wg[:,64:128] | sg@Ws}
        floatx4 acc[12] = {};
        const __half* ap = &tile[wv * 16 + n][q * 8];
        const __half* wp = Wfpq + q * 128 + n * 8;
        #pragma unroll
        for (int g = 0; g < 3; ++g) {
            #pragma unroll
            for (int kc = 0; kc < 2; ++kc) {
                half8 a = *(const half8*)(ap + g * 64 + kc * 32);
                #pragma unroll
                for (int tt = 0; tt < 4; ++tt) {
                    int t = g * 4 + tt;
                    half8 bf = *(const half8*)(wp + (size_t)(kc * 12 + t) * 512);
                    acc[t] = mfma16(a, bf, acc[t]);
                }
            }
        }
        // overwrite the wave's tile stripe in place (reads above already done;
        // DS ops are in-order per wave)
        #pragma unroll
        for (int t = 0; t < 12; ++t) {
            float bb = (t < 8) ? gat_b[t * 16 + n] : sg_b[(t - 8) * 16 + n];
            #pragma unroll
            for (int r = 0; r < 4; ++r) {
                float v = fmaxf(acc[t][r] + bb, 0.f);
                tile[wv * 16 + q * 4 + r][t * 16 + n] = __float2half(v);
            }
        }
    }
    {   // pre(l1) GEMM: K=192 from tile -> xh_out + layer-1 att dots
        floatx4 acc[4] = {};
        const __half* ap2 = &tile[wv * 16 + n][q * 8];
        const __half* wp = Wfpre + q * 128 + n * 8;
        #pragma unroll
        for (int kc = 0; kc < 6; ++kc) {
            half8 a = *(const half8*)(ap2 + kc * 32);
            #pragma unroll
            for (int t = 0; t < 4; ++t) {
                half8 bf = *(const half8*)(wp + (size_t)(kc * 4 + t) * 512);
                acc[t] = mfma16(a, bf, acc[t]);
            }
        }
        pre_epi(acc, pre_b, attf, asd_out, adst_out, xh_out, rowb, q, n);
    }
}

// ---------------- layer 1: agg(64 nodes) -> LDS -> post GEMM -> cls+logsoftmax
__global__ __launch_bounds__(256) void k_lay1(const int* __restrict__ row_ptr,
                                              const int2* __restrict__ recs,
                                              const float* __restrict__ asd_in,
                                              const float* __restrict__ adst_in,
                                              const __half* __restrict__ xh_in,
                                              const __half* __restrict__ Wfpq,
                                              const float* __restrict__ gat_b,
                                              const float* __restrict__ sg_b,
                                              const __half* __restrict__ Wfcls,
                                              const float* __restrict__ cb,
                                              float* __restrict__ out) {
    __shared__ __half tile[64][200];
    __shared__ float4 einfo[4][64];
    int lane = threadIdx.x & 63, wv = threadIdx.x >> 6;
    int sub = lane >> 5;
    unsigned flb = (unsigned)(lane & 31) * 4u;
    const float4* asd4 = (const float4*)asd_in;
    int base = blockIdx.x * 64 + wv * 16;
    for (int i = 0; i < 16; ++i) {
        int d = base + i;
        __half* trow = &tile[wv * 16 + i][0];
        if (d < NN) {
            agg_node(d, lane, sub, flb, row_ptr, recs, asd4, adst_in, xh_in,
                     einfo[wv], trow);
        } else {
            for (int c = lane; c < 192; c += 64) trow[c] = __float2half(0.f);
        }
    }
    int q = lane >> 4, n = lane & 15;
    int rowb = base;
    {
        floatx4 acc[12] = {};
        const __half* ap = &tile[wv * 16 + n][q * 8];
        const __half* wp = Wfpq + q * 128 + n * 8;
        #pragma unroll
        for (int g = 0; g < 3; ++g) {
            #pragma unroll
            for (int kc = 0; kc < 2; ++kc) {
                half8 a = *(const half8*)(ap + g * 64 + kc * 32);
                #pragma unroll
                for (int tt = 0; tt < 4; ++tt) {
                    int t = g * 4 + tt;
                    half8 bf = *(const half8*)(wp + (size_t)(kc * 12 + t) * 512);
                    acc[t] = mfma16(a, bf, acc[t]);
                }
            }
        }
        #pragma unroll
        for (int t = 0; t < 12; ++t) {
            float bb = (t < 8) ? gat_b[t * 16 + n] : sg_b[(t - 8) * 16 + n];
            #pragma unroll
            for (int r = 0; r < 4; ++r) {
                float v = fmaxf(acc[t][r] + bb, 0.f);
                tile[wv * 16 + q * 4 + r][t * 16 + n] = __float2half(v);
            }
        }
    }
    {
        floatx4 acc[2] = {};
        const __half* ap2 = &tile[wv * 16 + n][q * 8];
        const __half* wp = Wfcls + q * 128 + n * 8;
        #pragma unroll
        for (int kc = 0; kc < 6; ++kc) {
            half8 a = *(const half8*)(ap2 + kc * 32);
            #pragma unroll
            for (int t = 0; t < 2; ++t) {
                half8 bf = *(const half8*)(wp + (size_t)(kc * 2 + t) * 512);
                acc[t] = mfma16(a, bf, acc[t]);
            }
        }
        float b0 = cb[n], b1 = cb[16 + n];
        #pragma unroll
        for (int r = 0; r < 4; ++r) {
            float v0 = acc[0][r] + b0, v1 = acc[1][r] + b1;
            float mx = fmaxf(v0, v1);
            #pragma unroll
            for (int off = 1; off < 16; off <<= 1) mx = fmaxf(mx, __shfl_xor(mx, off));
            float sm = __expf(v0 - mx) + __expf(v1 - mx);
            #pragma unroll
            for (int off = 1; off < 16; off <<= 1) sm += __shfl_xor(sm, off);
            float lg = mx + __logf(sm);
            int row = rowb + q * 4 + r;
            if (row < NN) {
                out[(size_t)row * 32 + n]      = v0 - lg;
                out[(size_t)row * 32 + 16 + n] = v1 - lg;
            }
        }
    }
}

// ------------------------------------------------------------------------------
extern "C" void kernel_launch(void* const* d_in, const int* in_sizes, int n_in,
                              void* d_out, int out_size, void* d_ws, size_t ws_size,
                              hipStream_t stream) {
    const float* x   = (const float*)d_in[0];
    const int*   ei  = (const int*)d_in[1];
    const float* ew  = (const float*)d_in[2];
    const int* src = ei;
    const int* dst = ei + NE;

    const float* P[2][8];
    for (int l = 0; l < 2; ++l)
        for (int j = 0; j < 8; ++j)
            P[l][j] = (const float*)d_in[3 + l * 8 + j];
    const float* cls_W = (const float*)d_in[19];
    const float* cls_b = (const float*)d_in[20];

    float* ws = (float*)d_ws;
    const size_t n = NN;
    __half* xh0  = (__half*)(ws);             // [NN][64] halves = 32N fl
    __half* xh1  = (__half*)(ws + 32 * n);    // [NN][64] halves = 32N fl
    float* asd0  = ws + 64 * n;               // [NN]{as0,as1,dinv,pad} = 4N fl
    float* asd1  = ws + 68 * n;               // 4N
    float* adst0 = ws + 72 * n;               // 2N
    float* adst1 = ws + 74 * n;               // 2N
    __half* Wf   = (__half*)(ws + 76 * n);    // 59392 halves = 29696 fl
    float* attf  = ws + 76 * n + 29696;       // 512 fl
    float* base2 = ws + 76 * n + 30208;       // even offset -> 8B aligned
    unsigned long long* packed = (unsigned long long*)base2;  // NN u64
    unsigned long long* desc   = packed + NN;            // NBLK u64 (lookback)
    int*   row_ptr    = (int*)(desc + NBLK);             // NN+2
    int*   ord        = row_ptr + (NN + 2);              // NE
    int2*  recs       = (int2*)(ord + NE);               // NE (8B-aligned)

    __half* Wf_pre1 = Wf + 16384;
    __half* Wf_pq0  = Wf + 28672;
    __half* Wf_pq1  = Wf + 40960;
    __half* Wf_cls  = Wf + 53248;

    const int TB = 256;

    // ---- W0 swizzle first (3 us) so prep's pre32 blocks can read it ----
    hipMemsetAsync(packed, 0, (NN + NBLK) * sizeof(unsigned long long), stream);
    k_wpre0<<<64, TB, 0, stream>>>(P[0][0], Wf);

    // ---- mega-prep: pre32 GEMM | histogram+ordinal | W swizzles+attf ----
    k_prep<<<GB64 + HB + WB2, TB, 0, stream>>>(
        dst, ew, packed, ord, x, P[0][1],
        P[1][0], P[0][2], P[0][6], P[1][2], P[1][6], cls_W,
        P[0][3], P[0][4], P[1][3], P[1][4],
        Wf, attf, asd0, adst0, xh0);

    // ---- single-launch decoupled-lookback scan + fill ----
    k_scan<<<NBLK, TB, 0, stream>>>(packed, row_ptr, asd0, asd1, desc);
    k_fill<<<HB, TB, 0, stream>>>(src, dst, ew, row_ptr, ord, recs);

    // ---- fused layers: agg -> LDS -> post GEMM -> (pre | cls) ----
    k_lay0<<<GB64, TB, 0, stream>>>(row_ptr, recs, asd0, adst0, xh0,
                                    Wf_pq0, P[0][5], P[0][7],
                                    Wf_pre1, P[1][1], attf + 256,
                                    asd1, adst1, xh1);
    k_lay1<<<GB64, TB, 0, stream>>>(row_ptr, recs, asd1, adst1, xh1,
                                    Wf_pq1, P[1][5], P[1][7],
                                    Wf_cls, cls_b, (float*)d_out);
}

// Round 6
// 466.710 us; speedup vs baseline: 1.3679x; 1.3679x over previous
//
#include <hip/hip_runtime.h>
#include <hip/hip_fp16.h>
#include <math.h>

#define NN 100000
#define NE 1200000
#define FIN 256
#define NBLK 391        // (NN + 255) / 256
#define HB 4688         // (NE + 255) / 256  -- histogram blocks
#define WB2 170         // (59904 - 16384) / 256 -- W-swizzle blocks (skip pre0)
#define GB64 1563       // (NN + 63) / 64  -- 64-row GEMM blocks

using half8   = __attribute__((ext_vector_type(8))) _Float16;
using floatx4 = __attribute__((ext_vector_type(4))) float;

__device__ __forceinline__ floatx4 mfma16(half8 a, half8 b, floatx4 c) {
    return __builtin_amdgcn_mfma_f32_16x16x32_f16(a, b, c, 0, 0, 0);
}

// ---------------- W0 pre-swizzle (runs before k_prep so pre32 can read it) ----
__global__ __launch_bounds__(256) void k_wpre0(const float* __restrict__ W0,
                                               __half* __restrict__ Wf) {
    int o = blockIdx.x * 256 + threadIdx.x;   // 0..16383 exactly
    int j = o & 7, n = (o >> 3) & 15, q = (o >> 7) & 3, rest = o >> 9;
    int t = rest & 3, kc = rest >> 2;
    int k = kc * 32 + q * 8 + j, col = t * 16 + n;
    Wf[o] = __float2half(W0[(size_t)k * 64 + col]);
}

// ---------------- shared epilogue for pre-linear: store xh + att dots ---------
// asd row = {a_src0, a_src1, dinv, pad}; dinv slot untouched here.
__device__ __forceinline__ void pre_epi(floatx4* acc, const float* b, const float* attf,
                                        float* asd, float* a_dst, __half* out,
                                        int rowb, int q, int n) {
    float vs0[4] = {0,0,0,0}, vs1[4] = {0,0,0,0};
    float vd0[4] = {0,0,0,0}, vd1[4] = {0,0,0,0};
    #pragma unroll
    for (int t = 0; t < 4; ++t) {
        float bb  = b[t * 16 + n];
        float ws0 = attf[t * 16 + n],       ws1 = attf[64 + t * 16 + n];
        float wd0 = attf[128 + t * 16 + n], wd1 = attf[192 + t * 16 + n];
        #pragma unroll
        for (int r = 0; r < 4; ++r) {
            float xv = acc[t][r] + bb;
            int row = rowb + q * 4 + r;
            if (row < NN) out[(size_t)row * 64 + t * 16 + n] = __float2half(xv);
            vs0[r] = fmaf(xv, ws0, vs0[r]);
            vs1[r] = fmaf(xv, ws1, vs1[r]);
            vd0[r] = fmaf(xv, wd0, vd0[r]);
            vd1[r] = fmaf(xv, wd1, vd1[r]);
        }
    }
    #pragma unroll
    for (int off = 1; off < 16; off <<= 1) {
        #pragma unroll
        for (int r = 0; r < 4; ++r) {
            vs0[r] += __shfl_xor(vs0[r], off);
            vs1[r] += __shfl_xor(vs1[r], off);
            vd0[r] += __shfl_xor(vd0[r], off);
            vd1[r] += __shfl_xor(vd1[r], off);
        }
    }
    if (n == 0) {
        #pragma unroll
        for (int r = 0; r < 4; ++r) {
            int row = rowb + q * 4 + r;
            if (row < NN) {
                *(float2*)&asd[row * 4] = make_float2(vs0[r], vs1[r]);
                *(float2*)&a_dst[row * 2] = make_float2(vd0[r], vd1[r]);
            }
        }
    }
}

// ---------------- mega-prep: pre32 GEMM | histogram/ordinal | W swizzle -------
// pre32 blocks (MFMA-bound) co-scheduled with hist blocks (atomic-latency-bound)
// -> GEMM hides under atomics. Only 1KB static LDS: occupancy stays launch-bound.
// packed[d]: bits[48:63] = count, bits[0:47] = sum(w) in 2^-32 fixed point.
__global__ __launch_bounds__(256) void k_prep(const int* __restrict__ dst,
                                              const float* __restrict__ ew,
                                              unsigned long long* __restrict__ packed,
                                              int* __restrict__ ord,
                                              const float* __restrict__ x,
                                              const float* __restrict__ pre_b0,
                                              const float* __restrict__ W1,
                                              const float* __restrict__ Wg0,
                                              const float* __restrict__ Ws0,
                                              const float* __restrict__ Wg1,
                                              const float* __restrict__ Ws1,
                                              const float* __restrict__ Wc,
                                              const float* __restrict__ As0,
                                              const float* __restrict__ Ad0,
                                              const float* __restrict__ As1,
                                              const float* __restrict__ Ad1,
                                              __half* __restrict__ Wf,
                                              float* __restrict__ attf,
                                              float* __restrict__ asd,
                                              float* __restrict__ a_dst,
                                              __half* __restrict__ xh) {
    __shared__ float attL[256];
    int bid = blockIdx.x;
    int tid = threadIdx.x;
    if (bid >= GB64) {
        int b2 = bid - GB64;
        if (b2 < HB) {
            // ---- edge histogram + ordinal capture ----
            int e = b2 * 256 + tid;
            if (e >= NE) return;
            int d = dst[e]; float w = ew[e];
            unsigned long long add = (1ULL << 48)
                + (unsigned long long)((double)w * 4294967296.0);
            unsigned long long old = atomicAdd(&packed[d], add);
            ord[e] = (int)(old >> 48);
            return;
        }
        // ---- W swizzle (pre1, pq0, pq1, cls) + folded att vectors ----
        int o = (b2 - HB) * 256 + tid + 16384;
        if (o >= 59904) return;
        if (o >= 59392) {
            int idx = o - 59392;          // 0..511
            int layer = idx >> 8, rem = idx & 255;
            int v = rem >> 6, c = rem & 63, h = v & 1;
            const float* Wg = layer ? Wg1 : Wg0;
            const float* av = (v < 2) ? (layer ? As1 : As0) : (layer ? Ad1 : Ad0);
            float s = 0.f;
            for (int jj = 0; jj < 64; ++jj)
                s = fmaf(Wg[c * 128 + h * 64 + jj], av[h * 64 + jj], s);
            attf[idx] = s;
            return;
        }
        int lo, NT, N; const float* Wg; const float* Wsg = nullptr;
        if (o < 28672)      { lo = o - 16384; NT = 4;  N = 64; Wg = W1; }
        else if (o < 40960) { lo = o - 28672; NT = 12; N = 0;  Wg = Wg0; Wsg = Ws0; }
        else if (o < 53248) { lo = o - 40960; NT = 12; N = 0;  Wg = Wg1; Wsg = Ws1; }
        else                { lo = o - 53248; NT = 2;  N = 32; Wg = Wc; }
        int j = lo & 7, n = (lo >> 3) & 15, q = (lo >> 7) & 3, rest = lo >> 9;
        int t = rest % NT, kc = rest / NT;
        int k = kc * 32 + q * 8 + j, col = t * 16 + n;
        float v;
        if (Wsg) v = (col < 128) ? Wg[(size_t)k * 128 + col] : Wsg[(size_t)k * 64 + (col - 128)];
        else     v = Wg[(size_t)k * N + col];
        Wf[o] = __float2half(v);
        return;
    }
    // ---- pre32: xh = x @ W0 + b -> fp16, + layer-0 att dots (attL in-block) --
    {
        int v = tid >> 6, c = tid & 63, h = v & 1;
        const float* av = (v < 2) ? As0 : Ad0;
        float s = 0.f;
        for (int jj = 0; jj < 64; ++jj)
            s = fmaf(Wg0[c * 128 + h * 64 + jj], av[h * 64 + jj], s);
        attL[tid] = s;
    }
    __syncthreads();
    int lane = tid & 63, wv = tid >> 6;
    int q = lane >> 4, n = lane & 15;
    int rowb = bid * 64 + wv * 16;
    int rowA = rowb + n; if (rowA > NN - 1) rowA = NN - 1;
    floatx4 acc[4] = {};
    const float* ap = x + (size_t)rowA * FIN + q * 8;
    const __half* wp = Wf + q * 128 + n * 8;
    #pragma unroll
    for (int kc = 0; kc < FIN / 32; ++kc) {
        float4 f0 = *(const float4*)(ap + kc * 32);
        float4 f1 = *(const float4*)(ap + kc * 32 + 4);
        half8 a;
        a[0] = (_Float16)f0.x; a[1] = (_Float16)f0.y;
        a[2] = (_Float16)f0.z; a[3] = (_Float16)f0.w;
        a[4] = (_Float16)f1.x; a[5] = (_Float16)f1.y;
        a[6] = (_Float16)f1.z; a[7] = (_Float16)f1.w;
        #pragma unroll
        for (int t = 0; t < 4; ++t) {
            half8 bf = *(const half8*)(wp + (size_t)(kc * 4 + t) * 512);
            acc[t] = mfma16(a, bf, acc[t]);
        }
    }
    pre_epi(acc, pre_b0, attL, asd, a_dst, xh, rowb, q, n);
}

// ---------------- single-launch CSR scan: decoupled lookback ------------------
__global__ __launch_bounds__(256) void k_scan(const unsigned long long* __restrict__ packed,
                                              int* __restrict__ row_ptr,
                                              float* __restrict__ asd,
                                              unsigned long long* __restrict__ desc) {
    __shared__ int tmp[256];
    __shared__ int exoff_sh;
    int tid = threadIdx.x, bid = blockIdx.x;
    int i = bid * 256 + tid;
    int v = 0;
    if (i < NN) {
        unsigned long long p = packed[i];
        v = (int)(p >> 48);
        // +1.0 = virtual self-loop weight; deg >= 1 always
        double deg = (double)(p & 0xFFFFFFFFFFFFULL) * (1.0 / 4294967296.0) + 1.0;
        asd[i * 4 + 2] = rsqrtf((float)deg);
    }
    tmp[tid] = v;
    __syncthreads();
    for (int off = 1; off < 256; off <<= 1) {
        int t = (tid >= off) ? tmp[tid - off] : 0;
        __syncthreads();
        tmp[tid] += t;
        __syncthreads();
    }
    int bsum = tmp[255];
    if (bid == 0) {
        if (tid == 0) {
            exoff_sh = 0;
            atomicExch(&desc[0], (2ULL << 32) | (unsigned long long)(unsigned)bsum);
            row_ptr[NN] = NE;
        }
    } else if (tid < 64) {
        if (tid == 0)
            atomicExch(&desc[bid], (1ULL << 32) | (unsigned long long)(unsigned)bsum);
        int sum = 0;
        int base = bid - 1;
        for (;;) {
            int j = base - tid;
            unsigned long long d = 0;
            bool have = (j >= 0);
            if (have) {
                do { d = atomicAdd((unsigned long long*)&desc[j], 0ULL); }
                while ((d >> 32) == 0ULL);
            }
            unsigned long long m2 = __ballot(have && ((d >> 32) == 2ULL));
            if (m2) {
                int stop = __ffsll((long long)m2) - 1;   // nearest inclusive entry
                if (tid <= stop) sum += (int)(d & 0xFFFFFFFFULL);
                break;
            }
            if (have) sum += (int)(d & 0xFFFFFFFFULL);
            base -= 64;
        }
        #pragma unroll
        for (int off = 32; off; off >>= 1) sum += __shfl_xor(sum, off);
        if (tid == 0) {
            exoff_sh = sum;
            atomicExch(&desc[bid],
                       (2ULL << 32) | (unsigned long long)(unsigned)(sum + bsum));
        }
    }
    __syncthreads();
    if (i < NN) row_ptr[i] = exoff_sh + tmp[tid] - v;
}

// ---------------- CSR fill: NO atomic, NO dinv gather -------------------------
__global__ __launch_bounds__(256) void k_fill(const int* __restrict__ src,
                                              const int* __restrict__ dst,
                                              const float* __restrict__ ew,
                                              const int* __restrict__ row_ptr,
                                              const int* __restrict__ ord,
                                              int2* __restrict__ recs) {
    int e = blockIdx.x * 256 + threadIdx.x;
    if (e >= NE) return;
    int d = dst[e];
    int pos = row_ptr[d] + ord[e];
    int2 r; r.x = src[e]; r.y = __float_as_int(ew[e]);
    recs[pos] = r;
}

// ---------------- fused GAT + SG aggregation in xh-space (64-wide) ------------
// One wave per dst. QUARTER-WAVE edge processing: each 16-lane group handles one
// edge with an 8B half4 load (halves the loop iterations vs half-wave/half2).
__global__ __launch_bounds__(256) void k_agg(const int* __restrict__ row_ptr,
                                             const int2* __restrict__ recs,
                                             const float* __restrict__ asd,
                                             const float* __restrict__ a_dst,
                                             const __half* __restrict__ xh,
                                             __half* __restrict__ agg) {
    __shared__ float4 einfo[4][64];
    int lane = threadIdx.x & 63;
    int wv = threadIdx.x >> 6;
    int d = blockIdx.x * 4 + wv;
    if (d >= NN) return;
    int p0 = row_ptr[d], p1 = row_ptr[d + 1];
    int nn = p1 - p0;                 // real edges; +1 virtual self-loop
    float2 ad2 = ((const float2*)a_dst)[d];
    const float4* asd4 = (const float4*)asd;
    float4* einfoW = einfo[wv];
    int sub4 = lane >> 4;
    unsigned flb = (unsigned)(lane & 15) * 8u;   // byte offset of this lane's half4

    // accumulators: 4 features/lane for each of {gat_h0, gat_h1, sg}
    float g00 = 0.f, g01 = 0.f, g02 = 0.f, g03 = 0.f;
    float g10 = 0.f, g11 = 0.f, g12 = 0.f, g13 = 0.f;
    float sa0 = 0.f, sa1 = 0.f, sa2 = 0.f, sa3 = 0.f;

#define EDGE_ACC(E) do {                                                        \
        unsigned off_ = (unsigned)__float_as_int((E).w) + flb;                  \
        float2 raw_ = *(const float2*)((const char*)xh + off_);                 \
        float2 f0_ = __half22float2(*(__half2*)&raw_.x);                        \
        float2 f1_ = __half22float2(*(__half2*)&raw_.y);                        \
        g00 = fmaf((E).x, f0_.x, g00); g01 = fmaf((E).x, f0_.y, g01);           \
        g02 = fmaf((E).x, f1_.x, g02); g03 = fmaf((E).x, f1_.y, g03);           \
        g10 = fmaf((E).y, f0_.x, g10); g11 = fmaf((E).y, f0_.y, g11);           \
        g12 = fmaf((E).y, f1_.x, g12); g13 = fmaf((E).y, f1_.y, g13);           \
        sa0 = fmaf((E).z, f0_.x, sa0); sa1 = fmaf((E).z, f0_.y, sa1);           \
        sa2 = fmaf((E).z, f1_.x, sa2); sa3 = fmaf((E).z, f1_.y, sa3);           \
    } while (0)

    if (nn <= 63) {
        // ---- fast path (max degree ~40 for this graph) ----
        int tot = nn + 1;
        float v0 = -INFINITY, v1 = -INFINITY, ewq = 0.f; int es = 0;
        if (lane < tot) {
            float wraw;
            if (lane < nn) {
                int2 rec = recs[p0 + lane];
                es = rec.x;
                wraw = __int_as_float(rec.y);
            } else { es = d; wraw = 1.f; }       // virtual self-loop
            float4 a4 = asd4[es];
            v0 = a4.x + ad2.x; v0 = (v0 > 0.f) ? v0 : 0.2f * v0;
            v1 = a4.y + ad2.y; v1 = (v1 > 0.f) ? v1 : 0.2f * v1;
            ewq = wraw * a4.z;                   // w * dinv[src]
        }
        float m0 = v0, m1 = v1;
        #pragma unroll
        for (int off = 32; off; off >>= 1) {
            m0 = fmaxf(m0, __shfl_xor(m0, off));
            m1 = fmaxf(m1, __shfl_xor(m1, off));
        }
        float e0 = (lane < tot) ? __expf(v0 - m0) : 0.f;
        float e1 = (lane < tot) ? __expf(v1 - m1) : 0.f;
        float s0 = e0, s1 = e1;
        #pragma unroll
        for (int off = 32; off; off >>= 1) {
            s0 += __shfl_xor(s0, off);
            s1 += __shfl_xor(s1, off);
        }
        if (lane < tot)
            einfoW[lane] = make_float4(e0 / (s0 + 1e-16f), e1 / (s1 + 1e-16f),
                                       ewq, __int_as_float(es << 7));
        // intra-wave LDS: DS pipe is in-order per wave, no barrier needed
        const float4* ep = einfoW + sub4;
        int j = 0;
        for (; j + 8 <= tot; j += 8) {
            float4 eA = ep[j];
            float4 eB = ep[j + 4];
            EDGE_ACC(eA);
            EDGE_ACC(eB);
        }
        for (; j + 4 <= tot; j += 4) {
            float4 eA = ep[j];
            EDGE_ACC(eA);
        }
        if (sub4 < tot - j) {
            float4 eT = ep[j];
            EDGE_ACC(eT);
        }
    } else {
        // ---- generic 3-pass path (degree > 63; dead for this graph) ----
        float4 aself = asd4[d];
        float sv0 = aself.x + ad2.x; sv0 = (sv0 > 0.f) ? sv0 : 0.2f * sv0;
        float sv1 = aself.y + ad2.y; sv1 = (sv1 > 0.f) ? sv1 : 0.2f * sv1;
        float m0 = sv0, m1 = sv1;
        for (int e = p0 + lane; e < p1; e += 64) {
            int s = recs[e].x;
            float4 a4 = asd4[s];
            float v0 = a4.x + ad2.x; v0 = (v0 > 0.f) ? v0 : 0.2f * v0;
            float v1 = a4.y + ad2.y; v1 = (v1 > 0.f) ? v1 : 0.2f * v1;
            m0 = fmaxf(m0, v0); m1 = fmaxf(m1, v1);
        }
        #pragma unroll
        for (int off = 32; off; off >>= 1) {
            m0 = fmaxf(m0, __shfl_xor(m0, off));
            m1 = fmaxf(m1, __shfl_xor(m1, off));
        }
        float s0 = 0.f, s1 = 0.f;
        for (int e = p0 + lane; e < p1; e += 64) {
            int s = recs[e].x;
            float4 a4 = asd4[s];
            float v0 = a4.x + ad2.x; v0 = (v0 > 0.f) ? v0 : 0.2f * v0;
            float v1 = a4.y + ad2.y; v1 = (v1 > 0.f) ? v1 : 0.2f * v1;
            s0 += __expf(v0 - m0); s1 += __expf(v1 - m1);
        }
        #pragma unroll
        for (int off = 32; off; off >>= 1) {
            s0 += __shfl_xor(s0, off);
            s1 += __shfl_xor(s1, off);
        }
        s0 += __expf(sv0 - m0); s1 += __expf(sv1 - m1);   // self contribution
        float inv0 = 1.f / (s0 + 1e-16f), inv1 = 1.f / (s1 + 1e-16f);
        for (int base = p0; base < p1; base += 64) {
            int e = base + lane;
            int nc = min(64, p1 - base);
            if (e < p1) {
                int2 rec = recs[e];
                int es = rec.x;
                float4 a4 = asd4[es];
                float v0 = a4.x + ad2.x; v0 = (v0 > 0.f) ? v0 : 0.2f * v0;
                float v1 = a4.y + ad2.y; v1 = (v1 > 0.f) ? v1 : 0.2f * v1;
                einfoW[lane] = make_float4(__expf(v0 - m0) * inv0,
                                           __expf(v1 - m1) * inv1,
                                           __int_as_float(rec.y) * a4.z,
                                           __int_as_float(es << 7));
            }
            const float4* ep = einfoW + sub4;
            int j = 0;
            for (; j + 4 <= nc; j += 4) {
                float4 eA = ep[j];
                EDGE_ACC(eA);
            }
            if (sub4 < nc - j) {
                float4 eT = ep[j];
                EDGE_ACC(eT);
            }
        }
        if (sub4 == 0) {   // virtual self-loop
            float4 eS = make_float4(__expf(sv0 - m0) * inv0,
                                    __expf(sv1 - m1) * inv1,
                                    aself.z, __int_as_float(d << 7));
            EDGE_ACC(eS);
        }
    }
#undef EDGE_ACC

    // combine the four quarter-wave partial sums
    #pragma unroll
    for (int off = 16; off <= 32; off <<= 1) {
        g00 += __shfl_xor(g00, off); g01 += __shfl_xor(g01, off);
        g02 += __shfl_xor(g02, off); g03 += __shfl_xor(g03, off);
        g10 += __shfl_xor(g10, off); g11 += __shfl_xor(g11, off);
        g12 += __shfl_xor(g12, off); g13 += __shfl_xor(g13, off);
        sa0 += __shfl_xor(sa0, off); sa1 += __shfl_xor(sa1, off);
        sa2 += __shfl_xor(sa2, off); sa3 += __shfl_xor(sa3, off);
    }

    float did = asd4[d].z;
    __half* op = agg + (size_t)d * 192;
    int grp = lane >> 4, fo = (lane & 15) * 4;
    __half2 lo, hi;
    if (grp == 0)      { lo = __floats2half2_rn(g00, g01); hi = __floats2half2_rn(g02, g03); }
    else if (grp == 1) { lo = __floats2half2_rn(g10, g11); hi = __floats2half2_rn(g12, g13); }
    else               { lo = __floats2half2_rn(sa0 * did, sa1 * did);
                         hi = __floats2half2_rn(sa2 * did, sa3 * did); }
    if (grp < 3) {
        uint2 u;
        u.x = *(unsigned*)&lo; u.y = *(unsigned*)&hi;
        *(uint2*)(op + grp * 64 + fo) = u;
    }
}

// ---------------- fused post(l0) + pre(l1): agg -> LDS tile -> xh, att dots ---
// xA intermediate never touches HBM.
__global__ __launch_bounds__(256) void k_postpre(const __half* __restrict__ A,
                                                 const __half* __restrict__ Wfpq,
                                                 const float* __restrict__ gat_b,
                                                 const float* __restrict__ sg_b,
                                                 const __half* __restrict__ Wfpre,
                                                 const float* __restrict__ pre_b,
                                                 const float* __restrict__ attf,
                                                 float* __restrict__ asd,
                                                 float* __restrict__ a_dst,
                                                 __half* __restrict__ xh) {
    __shared__ __half tile[64][200];   // pad 192->200 halves: break bank aliasing
    int lane = threadIdx.x & 63, wv = threadIdx.x >> 6;
    int q = lane >> 4, n = lane & 15;
    int rowb = blockIdx.x * 64 + wv * 16;
    int rowA = rowb + n; if (rowA > NN - 1) rowA = NN - 1;
    {
        floatx4 acc[12] = {};
        const __half* ap = A + (size_t)rowA * 192 + q * 8;
        const __half* wp = Wfpq + q * 128 + n * 8;
        #pragma unroll
        for (int g = 0; g < 3; ++g) {
            #pragma unroll
            for (int kc = 0; kc < 2; ++kc) {
                half8 a = *(const half8*)(ap + g * 64 + kc * 32);
                #pragma unroll
                for (int tt = 0; tt < 4; ++tt) {
                    int t = g * 4 + tt;
                    half8 bf = *(const half8*)(wp + (size_t)(kc * 12 + t) * 512);
                    acc[t] = mfma16(a, bf, acc[t]);
                }
            }
        }
        #pragma unroll
        for (int t = 0; t < 12; ++t) {
            float bb = (t < 8) ? gat_b[t * 16 + n] : sg_b[(t - 8) * 16 + n];
            #pragma unroll
            for (int r = 0; r < 4; ++r) {
                int row = rowb + q * 4 + r;
                float v = fmaxf(acc[t][r] + bb, 0.f);
                tile[wv * 16 + q * 4 + r][t * 16 + n] =
                    (row < NN) ? __float2half(v) : __half(0.f);
            }
        }
    }
    __syncthreads();
    {
        floatx4 acc[4] = {};
        const __half* ap2 = &tile[wv * 16 + n][q * 8];
        const __half* wp = Wfpre + q * 128 + n * 8;
        #pragma unroll
        for (int kc = 0; kc < 6; ++kc) {
            half8 a = *(const half8*)(ap2 + kc * 32);
            #pragma unroll
            for (int t = 0; t < 4; ++t) {
                half8 bf = *(const half8*)(wp + (size_t)(kc * 4 + t) * 512);
                acc[t] = mfma16(a, bf, acc[t]);
            }
        }
        pre_epi(acc, pre_b, attf, asd, a_dst, xh, rowb, q, n);
    }
}

// ---------------- fused post(l1) + classifier + log_softmax -------------------
__global__ __launch_bounds__(256) void k_postcls(const __half* __restrict__ A,
                                                 const __half* __restrict__ Wfpq,
                                                 const float* __restrict__ gat_b,
                                                 const float* __restrict__ sg_b,
                                                 const __half* __restrict__ Wfcls,
                                                 const float* __restrict__ b,
                                                 float* __restrict__ out) {
    __shared__ __half tile[64][200];
    int lane = threadIdx.x & 63, wv = threadIdx.x >> 6;
    int q = lane >> 4, n = lane & 15;
    int rowb = blockIdx.x * 64 + wv * 16;
    int rowA = rowb + n; if (rowA > NN - 1) rowA = NN - 1;
    {
        floatx4 acc[12] = {};
        const __half* ap = A + (size_t)rowA * 192 + q * 8;
        const __half* wp = Wfpq + q * 128 + n * 8;
        #pragma unroll
        for (int g = 0; g < 3; ++g) {
            #pragma unroll
            for (int kc = 0; kc < 2; ++kc) {
                half8 a = *(const half8*)(ap + g * 64 + kc * 32);
                #pragma unroll
                for (int tt = 0; tt < 4; ++tt) {
                    int t = g * 4 + tt;
                    half8 bf = *(const half8*)(wp + (size_t)(kc * 12 + t) * 512);
                    acc[t] = mfma16(a, bf, acc[t]);
                }
            }
        }
        #pragma unroll
        for (int t = 0; t < 12; ++t) {
            float bb = (t < 8) ? gat_b[t * 16 + n] : sg_b[(t - 8) * 16 + n];
            #pragma unroll
            for (int r = 0; r < 4; ++r) {
                int row = rowb + q * 4 + r;
                float v = fmaxf(acc[t][r] + bb, 0.f);
                tile[wv * 16 + q * 4 + r][t * 16 + n] =
                    (row < NN) ? __float2half(v) : __half(0.f);
            }
        }
    }
    __syncthreads();
    {
        floatx4 acc[2] = {};
        const __half* ap2 = &tile[wv * 16 + n][q * 8];
        const __half* wp = Wfcls + q * 128 + n * 8;
        #pragma unroll
        for (int kc = 0; kc < 6; ++kc) {
            half8 a = *(const half8*)(ap2 + kc * 32);
            #pragma unroll
            for (int t = 0; t < 2; ++t) {
                half8 bf = *(const half8*)(wp + (size_t)(kc * 2 + t) * 512);
                acc[t] = mfma16(a, bf, acc[t]);
            }
        }
        float b0 = b[n], b1 = b[16 + n];
        #pragma unroll
        for (int r = 0; r < 4; ++r) {
            float v0 = acc[0][r] + b0, v1 = acc[1][r] + b1;
            float mx = fmaxf(v0, v1);
            #pragma unroll
            for (int off = 1; off < 16; off <<= 1) mx = fmaxf(mx, __shfl_xor(mx, off));
            float sm = __expf(v0 - mx) + __expf(v1 - mx);
            #pragma unroll
            for (int off = 1; off < 16; off <<= 1) sm += __shfl_xor(sm, off);
            float lg = mx + __logf(sm);
            int row = rowb + q * 4 + r;
            if (row < NN) {
                out[(size_t)row * 32 + n]      = v0 - lg;
                out[(size_t)row * 32 + 16 + n] = v1 - lg;
            }
        }
    }
}

// ------------------------------------------------------------------------------
extern "C" void kernel_launch(void* const* d_in, const int* in_sizes, int n_in,
                              void* d_out, int out_size, void* d_ws, size_t ws_size,
                              hipStream_t stream) {
    const float* x   = (const float*)d_in[0];
    const int*   ei  = (const int*)d_in[1];
    const float* ew  = (const float*)d_in[2];
    const int* src = ei;
    const int* dst = ei + NE;

    const float* P[2][8];
    for (int l = 0; l < 2; ++l)
        for (int j = 0; j < 8; ++j)
            P[l][j] = (const float*)d_in[3 + l * 8 + j];
    const float* cls_W = (const float*)d_in[19];
    const float* cls_b = (const float*)d_in[20];

    float* ws = (float*)d_ws;
    const size_t n = NN;
    __half* xh_h = (__half*)(ws);             // [NN][64]  halves = 32N fl
    __half* agg  = (__half*)(ws + 32 * n);    // [NN][192] halves = 96N fl
    float* asd   = ws + 128 * n;              // [NN]{as0,as1,dinv,pad} = 4N fl
    float* a_dst = ws + 132 * n;              // 2N
    __half* Wf   = (__half*)(ws + 134 * n);   // 59392 halves = 29696 fl
    float* attf  = ws + 134 * n + 29696;      // 512 fl
    float* base2 = ws + 134 * n + 30208;      // even offset -> 8B aligned
    unsigned long long* packed = (unsigned long long*)base2;  // NN u64
    unsigned long long* desc   = packed + NN;            // NBLK u64 (lookback)
    int*   row_ptr    = (int*)(desc + NBLK);             // NN+2
    int*   ord        = row_ptr + (NN + 2);              // NE
    int2*  recs       = (int2*)(ord + NE);               // NE (8B-aligned)

    __half* Wf_pre1 = Wf + 16384;
    __half* Wf_pq0  = Wf + 28672;
    __half* Wf_pq1  = Wf + 40960;
    __half* Wf_cls  = Wf + 53248;

    const int TB = 256;
    int gb_wave4 = (NN + 3) / 4;

    // ---- W0 swizzle first (3 us) so prep's pre32 blocks can read it ----
    hipMemsetAsync(packed, 0, (NN + NBLK) * sizeof(unsigned long long), stream);
    k_wpre0<<<64, TB, 0, stream>>>(P[0][0], Wf);

    // ---- mega-prep: pre32 GEMM | histogram+ordinal | W swizzles+attf ----
    k_prep<<<GB64 + HB + WB2, TB, 0, stream>>>(
        dst, ew, packed, ord, x, P[0][1],
        P[1][0], P[0][2], P[0][6], P[1][2], P[1][6], cls_W,
        P[0][3], P[0][4], P[1][3], P[1][4],
        Wf, attf, asd, a_dst, xh_h);

    // ---- single-launch decoupled-lookback scan + fill ----
    k_scan<<<NBLK, TB, 0, stream>>>(packed, row_ptr, asd, desc);
    k_fill<<<HB, TB, 0, stream>>>(src, dst, ew, row_ptr, ord, recs);

    // ---- layer 0 ----
    k_agg    <<<gb_wave4, TB, 0, stream>>>(row_ptr, recs, asd, a_dst, xh_h, agg);
    k_postpre<<<GB64, TB, 0, stream>>>(agg, Wf_pq0, P[0][5], P[0][7],
                                       Wf_pre1, P[1][1], attf + 256,
                                       asd, a_dst, xh_h);
    // ---- layer 1 ----
    k_agg    <<<gb_wave4, TB, 0, stream>>>(row_ptr, recs, asd, a_dst, xh_h, agg);
    k_postcls<<<GB64, TB, 0, stream>>>(agg, Wf_pq1, P[1][5], P[1][7],
                                       Wf_cls, cls_b, (float*)d_out);
}